// Round 10
// baseline (921.996 us; speedup 1.0000x reference)
//
#include <hip/hip_runtime.h>
#include <hip/hip_bf16.h>

// ---------------------------------------------------------------------------
// LlamaAttentionWeight: fused QKV projection (fp32 via bf16 split-GEMM) + RoPE
//   x:(2,8192,2048) wq:(2048,2048) wk:(512,2048) wv:(512,2048) pos_offset:int
//   out: qh(2,16,8192,128) | kh(2,4,8192,128) | vh(2,4,8192,128)  (fp32, concat)
//
// C = xhi.whi + xhi.wlo + xlo.whi  (bf16 split products, error ~2^-17)
// Logical GEMM M=16384 N=3072 K'=192 sub-tiles of 32; sub-tile j selects:
//   j<64:(Ahi,Bhi)  64<=j<128:(Ahi,Blo)  j>=128:(Alo,Bhi)
//
// GEMM: 256x256 tile, 8 waves, 4-slot LDS pipeline depth-3 (T3/T4): per
//   sub-tile issue stage(j+3), s_waitcnt vmcnt(12) (counted, never 0 in
//   steady state), 2 raw s_barriers, 32 MFMA w/ setprio (T5). T2 swizzle:
//   [128][64]-packed slots, chunk ^= row&7 (0 measured conflicts at r5).
//   XCD-chunked block swizzle: each XCD owns 8 bm x 12 bn (A read ~once).
// Wave wc owns head (wc>>1) cols {(wc&1)*32+[0,32)} U {+64..} so the RoPE
// pair (d, d+64) sits in the same lane -> in-register RoPE epilogue.
// ---------------------------------------------------------------------------

typedef __attribute__((ext_vector_type(8))) short short8;   // 8 bf16 (4 VGPR)
typedef __attribute__((ext_vector_type(4))) float f32x4;

#define Q_BLOCK  33554432u   // 2*16*8192*128
#define V_BASE   41943040u   // Q_BLOCK + 2*4*8192*128

__device__ __forceinline__ unsigned short f2bf(float f) {
  unsigned u = __float_as_uint(f);
  u += 0x7FFFu + ((u >> 16) & 1u);       // RNE
  return (unsigned short)(u >> 16);
}
__device__ __forceinline__ float bf2f(unsigned short h) {
  return __uint_as_float(((unsigned)h) << 16);
}

// ---------------- fused prep: split x, split W, RoPE table -----------------
// blocks [0,2048): split x (hi/lo bf16)   [2048,2560): split W
// blocks [2560,2688): rope table (8192 x 64 float2)
__global__ void prep_kernel(const float* __restrict__ x,
                            const float* __restrict__ wq,
                            const float* __restrict__ wk,
                            const float* __restrict__ wv,
                            const int* __restrict__ pos_off,
                            unsigned short* __restrict__ Ahi,
                            unsigned short* __restrict__ Alo,
                            unsigned short* __restrict__ Bhi,
                            unsigned short* __restrict__ Blo,
                            float2* __restrict__ rt) {
  const int bid = blockIdx.x, t = threadIdx.x;
  if (bid < 2048) {                       // ---- split x: 8388608 float4 items
    int base = bid * 4096 + t;
    #pragma unroll
    for (int i = 0; i < 16; ++i) {
      int idx = base + i * 256;
      float4 v = ((const float4*)x)[idx];
      ushort4 h, l;
      h.x = f2bf(v.x); l.x = f2bf(v.x - bf2f(h.x));
      h.y = f2bf(v.y); l.y = f2bf(v.y - bf2f(h.y));
      h.z = f2bf(v.z); l.z = f2bf(v.z - bf2f(h.z));
      h.w = f2bf(v.w); l.w = f2bf(v.w - bf2f(h.w));
      ((ushort4*)Ahi)[idx] = h;
      ((ushort4*)Alo)[idx] = l;
    }
  } else if (bid < 2560) {                // ---- split W: 1572864 float4 items
    int base = (bid - 2048) * 3072 + t;
    #pragma unroll
    for (int i = 0; i < 12; ++i) {
      int idx = base + i * 256;
      int n = idx >> 9, k4 = idx & 511;
      const float* src;
      if (n < 2048)      src = wq + (size_t)n * 2048;
      else if (n < 2560) src = wk + (size_t)(n - 2048) * 2048;
      else               src = wv + (size_t)(n - 2560) * 2048;
      float4 v = ((const float4*)src)[k4];
      ushort4 h, l;
      h.x = f2bf(v.x); l.x = f2bf(v.x - bf2f(h.x));
      h.y = f2bf(v.y); l.y = f2bf(v.y - bf2f(h.y));
      h.z = f2bf(v.z); l.z = f2bf(v.z - bf2f(h.z));
      h.w = f2bf(v.w); l.w = f2bf(v.w - bf2f(h.w));
      ((ushort4*)Bhi)[idx] = h;
      ((ushort4*)Blo)[idx] = l;
    }
  } else {                                // ---- rope table: 524288 items
    __shared__ float sinv[64];
    if (t < 64) sinv[t] = (float)pow(10000.0, -(double)t / 64.0);
    __syncthreads();
    const int po = pos_off[0];
    int base = (bid - 2560) * 4096 + t;
    #pragma unroll
    for (int i = 0; i < 16; ++i) {
      int idx = base + i * 256;
      int trow = idx >> 6, j = idx & 63;
      float ang = (float)(trow + po) * sinv[j];     // fp32 product like ref
      double a = (double)ang;
      double k = rint(a * 0.15915494309189535);     // 1/(2*pi)
      double r = a - k * 6.283185307179586;         // 2*pi
      float rf = (float)r;
      rt[idx] = make_float2(cosf(rf), sinf(rf));
    }
  }
}

// ---------------- main GEMM + RoPE epilogue (256^2, 4-slot pipeline) -------
__global__ __launch_bounds__(512, 2) void gemm8_kernel(
    const unsigned short* __restrict__ Ahi, const unsigned short* __restrict__ Alo,
    const unsigned short* __restrict__ Bhi, const unsigned short* __restrict__ Blo,
    const float2* __restrict__ rt, float* __restrict__ out) {
  // 4 slots x (A 8192 + B 8192 shorts) = 65536 shorts = 128 KiB.
  // Each 256x32 half packed as [128][64]: row r -> (r&127, (r>>7)*32 + k).
  __shared__ __align__(16) unsigned short smem[65536];

  const int tid  = threadIdx.x;
  const int lane = tid & 63;
  const int wave = tid >> 6;        // 0..7
  const int wr   = wave >> 2;       // M half
  const int wc   = wave & 3;        // N quarter (head = wc>>1, col32 = wc&1)
  const int l15  = lane & 15, lk = lane >> 4;

  // XCD-chunked swizzle: XCD owns 8 bm x 12 bn (A panel read ~once from HBM)
  const int xcd = blockIdx.x & 7;
  const int loc = blockIdx.x >> 3;        // 0..95
  const int bm = xcd * 8 + loc / 12;      // 0..63
  const int bn = loc % 12;                // 0..11
  const int rowA = bm * 256;
  const int rowB = bn * 256;

  // staging precompute (rule 21: inverse-swizzled global source, linear dest)
  // load L in {0,1}: linear short offset o = L*4096 + tid*8 within a half
  int grow[2], gk[2];
  #pragma unroll
  for (int L = 0; L < 2; ++L) {
    const int o = L * 4096 + tid * 8;
    const int lr = o >> 6;                 // lds row 0..127
    const int cs = (o >> 3) & 7;           // stored 16B chunk
    const int cl = cs ^ (lr & 7);          // logical chunk
    grow[L] = lr + ((cl >> 2) << 7);       // logical matrix row 0..255
    gk[L]   = (cl & 3) << 3;               // k offset 0..24
  }

  // ds_read chunk columns (swizzled), constant per lane
  const int csA = ((wr << 2) + lk) ^ (l15 & 7);
  const int csB = (((wc >> 1) << 2) + lk) ^ (l15 & 7);

  f32x4 acc[8][4];
  #pragma unroll
  for (int m = 0; m < 8; ++m)
    #pragma unroll
    for (int n = 0; n < 4; ++n)
      acc[m][n] = (f32x4){0.f, 0.f, 0.f, 0.f};

  // stage sub-tile n into slot n&3 (4 gload_lds of 16B per thread)
  auto STAGE = [&](int n) {
    const unsigned short* As = (n < 128) ? Ahi : Alo;
    const unsigned short* Bs = (n < 64 || n >= 128) ? Bhi : Blo;
    const int kcol = (n & 63) << 5;
    const int sb = (n & 3) << 14;          // slot base (shorts)
    #pragma unroll
    for (int L = 0; L < 2; ++L) {
      const int o = L * 4096 + tid * 8;
      const unsigned short* ga = As + (size_t)(rowA + grow[L]) * 2048 + kcol + gk[L];
      __builtin_amdgcn_global_load_lds(
          (const __attribute__((address_space(1))) void*)ga,
          (__attribute__((address_space(3))) void*)&smem[sb + o], 16, 0, 0);
      const unsigned short* gb = Bs + (size_t)(rowB + grow[L]) * 2048 + kcol + gk[L];
      __builtin_amdgcn_global_load_lds(
          (const __attribute__((address_space(1))) void*)gb,
          (__attribute__((address_space(3))) void*)&smem[sb + 8192 + o], 16, 0, 0);
    }
  };

  // prologue: fill pipeline 3 deep
  STAGE(0); STAGE(1); STAGE(2);

  for (int j = 0; j < 192; ++j) {
    // bar1: all waves done READING slot (j+3)&3 == (j-1)&3 (compute j-1)
    if (j) __builtin_amdgcn_s_barrier();
    if (j + 3 < 192) STAGE(j + 3);
    // counted wait: only sub-tile j's 4 loads (oldest) must have landed
    if (j < 189)       asm volatile("s_waitcnt vmcnt(12)" ::: "memory");
    else if (j == 189) asm volatile("s_waitcnt vmcnt(8)"  ::: "memory");
    else if (j == 190) asm volatile("s_waitcnt vmcnt(4)"  ::: "memory");
    else               asm volatile("s_waitcnt vmcnt(0)"  ::: "memory");
    // bar2: every wave's stage of sub-tile j has landed
    __builtin_amdgcn_s_barrier();

    const int sb = (j & 3) << 14;
    short8 af[8], bf[4];
    #pragma unroll
    for (int mi = 0; mi < 8; ++mi)
      af[mi] = *(const short8*)&smem[sb + (mi * 16 + l15) * 64 + csA * 8];
    #pragma unroll
    for (int ni = 0; ni < 4; ++ni) {
      const int br = (wc & 1) * 32 + (ni & 1) * 16 + ((ni >> 1) << 6) + l15;
      bf[ni] = *(const short8*)&smem[sb + 8192 + br * 64 + csB * 8];
    }
    __builtin_amdgcn_s_setprio(1);
    #pragma unroll
    for (int mi = 0; mi < 8; ++mi)
      #pragma unroll
      for (int ni = 0; ni < 4; ++ni)
        acc[mi][ni] = __builtin_amdgcn_mfma_f32_16x16x32_bf16(
            af[mi], bf[ni], acc[mi][ni], 0, 0, 0);
    __builtin_amdgcn_s_setprio(0);
  }

  // ---- epilogue: RoPE in-register + head-transpose scatter ----
  const int headglob = bn * 2 + (wc >> 1);
  size_t base; int nheads, head; bool dorope;
  if (headglob < 16)      { base = 0;       head = headglob;      nheads = 16; dorope = true; }
  else if (headglob < 20) { base = Q_BLOCK; head = headglob - 16; nheads = 4;  dorope = true; }
  else                    { base = V_BASE;  head = headglob - 20; nheads = 4;  dorope = false; }
  const int dbase = (wc & 1) * 32;

  #pragma unroll
  for (int m = 0; m < 8; ++m) {
    #pragma unroll
    for (int r = 0; r < 4; ++r) {
      const int row = bm * 256 + wr * 128 + m * 16 + lk * 4 + r;
      const int b = row >> 13, trow = row & 8191;
      float* op = out + base + (((size_t)(b * nheads + head) * 8192 + trow) << 7);
      #pragma unroll
      for (int n0 = 0; n0 < 2; ++n0) {
        const int d1 = dbase + n0 * 16 + l15;          // [0,64)
        const float c1 = acc[m][n0][r];                // col d1
        const float c2 = acc[m][n0 + 2][r];            // col d1+64
        if (dorope) {
          const float2 cs = rt[(trow << 6) + d1];
          op[d1]      = c1 * cs.x - c2 * cs.y;
          op[d1 + 64] = c2 * cs.x + c1 * cs.y;
        } else {
          op[d1]      = c1;
          op[d1 + 64] = c2;
        }
      }
    }
  }
}

// ---------------- fallback: naive fp32, zero workspace ---------------------
__global__ void fallback_kernel(const float* __restrict__ x,
                                const float* __restrict__ wq,
                                const float* __restrict__ wk,
                                const float* __restrict__ wv,
                                const int* __restrict__ pos_off,
                                float* __restrict__ out) {
  __shared__ float xs[2048];
  const int m = blockIdx.x;
  const int b = m >> 13, t = m & 8191;
  const float* xr = x + (size_t)m * 2048;
  for (int i = threadIdx.x; i < 2048; i += 256) xs[i] = xr[i];
  __syncthreads();

  const int n = blockIdx.y * 256 + threadIdx.x;   // [0,1536)
  const int d = n & 63;
  const float* w; size_t base; int head, nh; bool dorope;
  if (n < 1024)      { head = n >> 6;          w = wq + (size_t)(head * 128 + d) * 2048; base = 0;       nh = 16; dorope = true; }
  else if (n < 1280) { head = (n - 1024) >> 6; w = wk + (size_t)(head * 128 + d) * 2048; base = Q_BLOCK; nh = 4;  dorope = true; }
  else               { head = (n - 1280) >> 6; w = wv + (size_t)(head * 128 + d) * 2048; base = V_BASE;  nh = 4;  dorope = false; }

  const float* w2 = w + 64 * 2048;
  float c1 = 0.f, c2 = 0.f;
  for (int k = 0; k < 2048; ++k) { c1 += xs[k] * w[k]; c2 += xs[k] * w2[k]; }

  float* op = out + base + (((size_t)(b * nh + head) * 8192 + t) << 7);
  if (dorope) {
    double invf = pow(10000.0, -(double)d / 64.0);
    float ang = (float)(t + pos_off[0]) * (float)invf;
    float cs = (float)cos((double)ang), sn = (float)sin((double)ang);
    op[d]      = c1 * cs - c2 * sn;
    op[d + 64] = c2 * cs + c1 * sn;
  } else {
    op[d]      = c1;
    op[d + 64] = c2;
  }
}

// ---------------------------------------------------------------------------
extern "C" void kernel_launch(void* const* d_in, const int* in_sizes, int n_in,
                              void* d_out, int out_size, void* d_ws, size_t ws_size,
                              hipStream_t stream) {
  const float* x  = (const float*)d_in[0];
  const float* wq = (const float*)d_in[1];
  const float* wk = (const float*)d_in[2];
  const float* wv = (const float*)d_in[3];
  const int* pos  = (const int*)d_in[4];
  float* out = (float*)d_out;

  // workspace layout (163.6 MB total)
  const size_t WS_NEEDED = 134217728ull + 25165824ull + 4194304ull;
  if (ws_size < WS_NEEDED) {
    fallback_kernel<<<dim3(16384, 6), 256, 0, stream>>>(x, wq, wk, wv, pos, out);
    return;
  }

  unsigned short* Ahi = (unsigned short*)d_ws;      // 33554432 bf16 = 67.1 MB
  unsigned short* Alo = Ahi + 33554432;             // 67.1 MB
  unsigned short* Bhi = Alo + 33554432;             // 3072*2048 = 12.6 MB
  unsigned short* Blo = Bhi + 6291456;              // 12.6 MB
  float2* rt = (float2*)(Blo + 6291456);            // 8192*64*8B = 4.2 MB

  prep_kernel<<<2688, 256, 0, stream>>>(x, wq, wk, wv, pos,
                                        Ahi, Alo, Bhi, Blo, rt);
  gemm8_kernel<<<768, 512, 0, stream>>>(Ahi, Alo, Bhi, Blo, rt, out);
}

// Round 11
// 847.774 us; speedup vs baseline: 1.0875x; 1.0875x over previous
//
#include <hip/hip_runtime.h>
#include <hip/hip_bf16.h>

// ---------------------------------------------------------------------------
// LlamaAttentionWeight: fused QKV projection (fp32 via bf16 split-GEMM) + RoPE
//   x:(2,8192,2048) wq:(2048,2048) wk:(512,2048) wv:(512,2048) pos_offset:int
//   out: qh(2,16,8192,128) | kh(2,4,8192,128) | vh(2,4,8192,128)  (fp32, concat)
//
// C = xhi.whi + xhi.wlo + xlo.whi  (bf16 split products, error ~2^-17)
// Logical GEMM M=16384 N=3072, 96 K-tiles of 64; tile t selects:
//   t<32:(Ahi,Bhi)  32<=t<64:(Ahi,Blo)  t>=64:(Alo,Bhi), kcol=(t&31)*64
//
// GEMM: m201 8-phase port. 256x256 tile, 8 waves (2M x 4N), BK=64,
//   2 LDS buffers x (A,B) x 2 halves x [128][64] shorts = 128 KiB.
//   4 phases per K-tile: ph1{read A-mh0(8)+B-nh0(4), stage A0(t+1)},
//   ph2{read B-nh1(4), stage A1(t+1)}, ph3{read A-mh1(8), stage B0(t+2)},
//   ph4{stage B1(t+2), vmcnt(4)}. Each phase: [reads][stage][bar][lgkmcnt0]
//   [setprio 16-MFMA] [bar]. Counted vmcnt once/tile (T4), setprio (T5),
//   chunk^row&7 swizzle both-sides (T2, 0 conflicts measured r5/r10),
//   XCD-chunked block swizzle (FETCH 1.29->0.67 GB measured r10).
// Wave wc owns head (wc>>1) cols {(wc&1)*32+[0,32)} U {+64..} so the RoPE
// pair (d, d+64) sits in the same lane -> in-register RoPE epilogue.
// ---------------------------------------------------------------------------

typedef __attribute__((ext_vector_type(8))) short short8;   // 8 bf16 (4 VGPR)
typedef __attribute__((ext_vector_type(4))) float f32x4;

#define Q_BLOCK  33554432u   // 2*16*8192*128
#define V_BASE   41943040u   // Q_BLOCK + 2*4*8192*128

__device__ __forceinline__ unsigned short f2bf(float f) {
  unsigned u = __float_as_uint(f);
  u += 0x7FFFu + ((u >> 16) & 1u);       // RNE
  return (unsigned short)(u >> 16);
}
__device__ __forceinline__ float bf2f(unsigned short h) {
  return __uint_as_float(((unsigned)h) << 16);
}

// ---------------- fused prep: split x, split W, RoPE table -----------------
__global__ void prep_kernel(const float* __restrict__ x,
                            const float* __restrict__ wq,
                            const float* __restrict__ wk,
                            const float* __restrict__ wv,
                            const int* __restrict__ pos_off,
                            unsigned short* __restrict__ Ahi,
                            unsigned short* __restrict__ Alo,
                            unsigned short* __restrict__ Bhi,
                            unsigned short* __restrict__ Blo,
                            float2* __restrict__ rt) {
  const int bid = blockIdx.x, t = threadIdx.x;
  if (bid < 2048) {                       // ---- split x: 8388608 float4 items
    int base = bid * 4096 + t;
    #pragma unroll
    for (int i = 0; i < 16; ++i) {
      int idx = base + i * 256;
      float4 v = ((const float4*)x)[idx];
      ushort4 h, l;
      h.x = f2bf(v.x); l.x = f2bf(v.x - bf2f(h.x));
      h.y = f2bf(v.y); l.y = f2bf(v.y - bf2f(h.y));
      h.z = f2bf(v.z); l.z = f2bf(v.z - bf2f(h.z));
      h.w = f2bf(v.w); l.w = f2bf(v.w - bf2f(h.w));
      ((ushort4*)Ahi)[idx] = h;
      ((ushort4*)Alo)[idx] = l;
    }
  } else if (bid < 2560) {                // ---- split W: 1572864 float4 items
    int base = (bid - 2048) * 3072 + t;
    #pragma unroll
    for (int i = 0; i < 12; ++i) {
      int idx = base + i * 256;
      int n = idx >> 9, k4 = idx & 511;
      const float* src;
      if (n < 2048)      src = wq + (size_t)n * 2048;
      else if (n < 2560) src = wk + (size_t)(n - 2048) * 2048;
      else               src = wv + (size_t)(n - 2560) * 2048;
      float4 v = ((const float4*)src)[k4];
      ushort4 h, l;
      h.x = f2bf(v.x); l.x = f2bf(v.x - bf2f(h.x));
      h.y = f2bf(v.y); l.y = f2bf(v.y - bf2f(h.y));
      h.z = f2bf(v.z); l.z = f2bf(v.z - bf2f(h.z));
      h.w = f2bf(v.w); l.w = f2bf(v.w - bf2f(h.w));
      ((ushort4*)Bhi)[idx] = h;
      ((ushort4*)Blo)[idx] = l;
    }
  } else {                                // ---- rope table: 524288 items
    __shared__ float sinv[64];
    if (t < 64) sinv[t] = (float)pow(10000.0, -(double)t / 64.0);
    __syncthreads();
    const int po = pos_off[0];
    int base = (bid - 2560) * 4096 + t;
    #pragma unroll
    for (int i = 0; i < 16; ++i) {
      int idx = base + i * 256;
      int trow = idx >> 6, j = idx & 63;
      float ang = (float)(trow + po) * sinv[j];     // fp32 product like ref
      double a = (double)ang;
      double k = rint(a * 0.15915494309189535);     // 1/(2*pi)
      double r = a - k * 6.283185307179586;         // 2*pi
      float rf = (float)r;
      rt[idx] = make_float2(cosf(rf), sinf(rf));
    }
  }
}

// ---------------- main GEMM + RoPE epilogue (m201 8-phase port) ------------
__global__ __launch_bounds__(512, 2) void gemm8_kernel(
    const unsigned short* __restrict__ Ahi, const unsigned short* __restrict__ Alo,
    const unsigned short* __restrict__ Bhi, const unsigned short* __restrict__ Blo,
    const float2* __restrict__ rt, float* __restrict__ out) {
  // 2 buffers x {A0,A1,B0,B1} halves x 8192 shorts = 65536 shorts = 128 KiB.
  // Half = 128 rows x 64 K, packed [128][64], stored chunk = logical ^ (row&7).
  __shared__ __align__(16) unsigned short smem[65536];

  const int tid  = threadIdx.x;
  const int lane = tid & 63;
  const int wave = tid >> 6;        // 0..7
  const int wr   = wave >> 2;       // M half
  const int wc   = wave & 3;        // N quarter (head = wc>>1, col32 = wc&1)
  const int l15  = lane & 15, lk = lane >> 4;

  // XCD-chunked swizzle (r10: FETCH 1.29 GB -> 0.67 GB)
  const int xcd = blockIdx.x & 7;
  const int loc = blockIdx.x >> 3;        // 0..95
  const int bm = xcd * 8 + loc / 12;      // 0..63
  const int bn = loc % 12;                // 0..11
  const int rowA = bm * 256;
  const int rowB = bn * 256;

  // staging precompute (rule 21: inverse-swizzled global source, linear dest)
  // half stage: per thread 2 loads, linear short offset o = L*4096 + tid*8
  int grow[2], gk[2];
  #pragma unroll
  for (int L = 0; L < 2; ++L) {
    const int o = L * 4096 + tid * 8;
    const int lr = o >> 6;                 // lds row 0..127 (local)
    const int cs = (o >> 3) & 7;           // stored 16B chunk
    const int cl = cs ^ (lr & 7);          // logical chunk 0..7
    grow[L] = lr;                          // row within the 128-row half
    gk[L]   = cl << 3;                     // k offset 0..56
  }

  // ds_read swizzled chunk offsets (shorts), constant per lane, kk in {0,1}
  const int ck0 = (((0 << 2) + lk) ^ (l15 & 7)) << 3;
  const int ck1 = (((1 << 2) + lk) ^ (l15 & 7)) << 3;

  f32x4 acc[8][4];
  #pragma unroll
  for (int m = 0; m < 8; ++m)
    #pragma unroll
    for (int n = 0; n < 4; ++n)
      acc[m][n] = (f32x4){0.f, 0.f, 0.f, 0.f};

  auto Asel = [&](int tt) { return (tt < 64) ? Ahi : Alo; };
  auto Bsel = [&](int tt) { return (tt < 32 || tt >= 64) ? Bhi : Blo; };

  // stage one 16 KB half (128 rows x 64 K): 2 gload_lds(16B) per thread
  auto STAGE = [&](int dst, const unsigned short* src, int rowbase, int kc) {
    #pragma unroll
    for (int L = 0; L < 2; ++L) {
      const int o = L * 4096 + tid * 8;
      const unsigned short* g = src + (size_t)(rowbase + grow[L]) * 2048 + kc + gk[L];
      __builtin_amdgcn_global_load_lds(
          (const __attribute__((address_space(1))) void*)g,
          (__attribute__((address_space(3))) void*)&smem[dst + o], 16, 0, 0);
    }
  };

  // ---- prologue: stage in steady-state issue order, then counted wait ----
  // order: B0(0) B1(0) A0(0) A1(0) B0(1) B1(1)  (6 events, 12 loads)
  STAGE(0 + 16384,     Bhi, rowB,       0);    // B0(0)
  STAGE(0 + 24576,     Bhi, rowB + 128, 0);    // B1(0)
  STAGE(0 + 0,         Ahi, rowA,       0);    // A0(0)
  STAGE(0 + 8192,      Ahi, rowA + 128, 0);    // A1(0)
  STAGE(32768 + 16384, Bhi, rowB,       64);   // B0(1)
  STAGE(32768 + 24576, Bhi, rowB + 128, 64);   // B1(1)
  asm volatile("s_waitcnt vmcnt(4)" ::: "memory");  // tile0's 4 halves landed
  __builtin_amdgcn_s_barrier();

  short8 afA[4][2], bf0[2][2], bf1[2][2];

  for (int t = 0; t < 96; ++t) {
    const int cb  = (t & 1) << 15;       // current buffer base (shorts)
    const int ob  = cb ^ 32768;          // other buffer
    const int aoff = cb + wr * 8192;     // this wave's A half
    const int boff = cb + 16384 + (wc >> 1) * 8192;  // this wave's B half
    const int brow0 = (wc & 1) * 32;

    // ======== phase 1: read A-mh0 (8) + B-nh0 (4); stage A0(t+1) ========
    #pragma unroll
    for (int mi = 0; mi < 4; ++mi) {
      const int r = mi * 16 + l15;
      afA[mi][0] = *(const short8*)&smem[aoff + r * 64 + ck0];
      afA[mi][1] = *(const short8*)&smem[aoff + r * 64 + ck1];
    }
    #pragma unroll
    for (int ni = 0; ni < 2; ++ni) {
      const int r = brow0 + ni * 16 + l15;
      bf0[ni][0] = *(const short8*)&smem[boff + r * 64 + ck0];
      bf0[ni][1] = *(const short8*)&smem[boff + r * 64 + ck1];
    }
    if (t < 95) STAGE(ob + 0, Asel(t + 1), rowA, ((t + 1) & 31) << 6);
    asm volatile("s_waitcnt lgkmcnt(8)" ::: "memory");
    __builtin_amdgcn_s_barrier();
    asm volatile("s_waitcnt lgkmcnt(0)" ::: "memory");
    __builtin_amdgcn_s_setprio(1);
    #pragma unroll
    for (int mi = 0; mi < 4; ++mi)
      #pragma unroll
      for (int ni = 0; ni < 2; ++ni)
        #pragma unroll
        for (int kk = 0; kk < 2; ++kk)
          acc[mi][ni] = __builtin_amdgcn_mfma_f32_16x16x32_bf16(
              afA[mi][kk], bf0[ni][kk], acc[mi][ni], 0, 0, 0);
    __builtin_amdgcn_s_setprio(0);
    __builtin_amdgcn_s_barrier();

    // ======== phase 2: read B-nh1 (4); stage A1(t+1) ========
    #pragma unroll
    for (int ni = 0; ni < 2; ++ni) {
      const int r = brow0 + 64 + ni * 16 + l15;
      bf1[ni][0] = *(const short8*)&smem[boff + r * 64 + ck0];
      bf1[ni][1] = *(const short8*)&smem[boff + r * 64 + ck1];
    }
    if (t < 95) STAGE(ob + 8192, Asel(t + 1), rowA + 128, ((t + 1) & 31) << 6);
    __builtin_amdgcn_s_barrier();
    asm volatile("s_waitcnt lgkmcnt(0)" ::: "memory");
    __builtin_amdgcn_s_setprio(1);
    #pragma unroll
    for (int mi = 0; mi < 4; ++mi)
      #pragma unroll
      for (int ni = 0; ni < 2; ++ni)
        #pragma unroll
        for (int kk = 0; kk < 2; ++kk)
          acc[mi][2 + ni] = __builtin_amdgcn_mfma_f32_16x16x32_bf16(
              afA[mi][kk], bf1[ni][kk], acc[mi][2 + ni], 0, 0, 0);
    __builtin_amdgcn_s_setprio(0);
    __builtin_amdgcn_s_barrier();

    // ======== phase 3: read A-mh1 (8); stage B0(t+2) ========
    #pragma unroll
    for (int mi = 0; mi < 4; ++mi) {
      const int r = 64 + mi * 16 + l15;
      afA[mi][0] = *(const short8*)&smem[aoff + r * 64 + ck0];
      afA[mi][1] = *(const short8*)&smem[aoff + r * 64 + ck1];
    }
    if (t < 94) STAGE(cb + 16384, Bsel(t + 2), rowB, ((t + 2) & 31) << 6);
    __builtin_amdgcn_s_barrier();
    asm volatile("s_waitcnt lgkmcnt(0)" ::: "memory");
    __builtin_amdgcn_s_setprio(1);
    #pragma unroll
    for (int mi = 0; mi < 4; ++mi)
      #pragma unroll
      for (int ni = 0; ni < 2; ++ni)
        #pragma unroll
        for (int kk = 0; kk < 2; ++kk)
          acc[4 + mi][ni] = __builtin_amdgcn_mfma_f32_16x16x32_bf16(
              afA[mi][kk], bf0[ni][kk], acc[4 + mi][ni], 0, 0, 0);
    __builtin_amdgcn_s_setprio(0);
    __builtin_amdgcn_s_barrier();

    // ======== phase 4: stage B1(t+2); counted vmcnt; MFMA q(1,1) ========
    if (t < 94) STAGE(cb + 24576, Bsel(t + 2), rowB + 128, ((t + 2) & 31) << 6);
    if (t < 94)       asm volatile("s_waitcnt vmcnt(4)" ::: "memory");
    else if (t == 94) asm volatile("s_waitcnt vmcnt(0)" ::: "memory");
    __builtin_amdgcn_s_barrier();
    __builtin_amdgcn_s_setprio(1);
    #pragma unroll
    for (int mi = 0; mi < 4; ++mi)
      #pragma unroll
      for (int ni = 0; ni < 2; ++ni)
        #pragma unroll
        for (int kk = 0; kk < 2; ++kk)
          acc[4 + mi][2 + ni] = __builtin_amdgcn_mfma_f32_16x16x32_bf16(
              afA[mi][kk], bf1[ni][kk], acc[4 + mi][2 + ni], 0, 0, 0);
    __builtin_amdgcn_s_setprio(0);
    __builtin_amdgcn_s_barrier();
  }

  // ---- epilogue: RoPE in-register + head-transpose scatter ----
  const int headglob = bn * 2 + (wc >> 1);
  size_t base; int nheads, head; bool dorope;
  if (headglob < 16)      { base = 0;       head = headglob;      nheads = 16; dorope = true; }
  else if (headglob < 20) { base = Q_BLOCK; head = headglob - 16; nheads = 4;  dorope = true; }
  else                    { base = V_BASE;  head = headglob - 20; nheads = 4;  dorope = false; }
  const int dbase = (wc & 1) * 32;

  #pragma unroll
  for (int m = 0; m < 8; ++m) {
    #pragma unroll
    for (int r = 0; r < 4; ++r) {
      const int row = bm * 256 + wr * 128 + m * 16 + lk * 4 + r;
      const int b = row >> 13, trow = row & 8191;
      float* op = out + base + (((size_t)(b * nheads + head) * 8192 + trow) << 7);
      #pragma unroll
      for (int n0 = 0; n0 < 2; ++n0) {
        const int d1 = dbase + n0 * 16 + l15;          // [0,64)
        const float c1 = acc[m][n0][r];                // col d1
        const float c2 = acc[m][n0 + 2][r];            // col d1+64
        if (dorope) {
          const float2 cs = rt[(trow << 6) + d1];
          op[d1]      = c1 * cs.x - c2 * cs.y;
          op[d1 + 64] = c2 * cs.x + c1 * cs.y;
        } else {
          op[d1]      = c1;
          op[d1 + 64] = c2;
        }
      }
    }
  }
}

// ---------------- fallback: naive fp32, zero workspace ---------------------
__global__ void fallback_kernel(const float* __restrict__ x,
                                const float* __restrict__ wq,
                                const float* __restrict__ wk,
                                const float* __restrict__ wv,
                                const int* __restrict__ pos_off,
                                float* __restrict__ out) {
  __shared__ float xs[2048];
  const int m = blockIdx.x;
  const int b = m >> 13, t = m & 8191;
  const float* xr = x + (size_t)m * 2048;
  for (int i = threadIdx.x; i < 2048; i += 256) xs[i] = xr[i];
  __syncthreads();

  const int n = blockIdx.y * 256 + threadIdx.x;   // [0,1536)
  const int d = n & 63;
  const float* w; size_t base; int head, nh; bool dorope;
  if (n < 1024)      { head = n >> 6;          w = wq + (size_t)(head * 128 + d) * 2048; base = 0;       nh = 16; dorope = true; }
  else if (n < 1280) { head = (n - 1024) >> 6; w = wk + (size_t)(head * 128 + d) * 2048; base = Q_BLOCK; nh = 4;  dorope = true; }
  else               { head = (n - 1280) >> 6; w = wv + (size_t)(head * 128 + d) * 2048; base = V_BASE;  nh = 4;  dorope = false; }

  const float* w2 = w + 64 * 2048;
  float c1 = 0.f, c2 = 0.f;
  for (int k = 0; k < 2048; ++k) { c1 += xs[k] * w[k]; c2 += xs[k] * w2[k]; }

  float* op = out + base + (((size_t)(b * nh + head) * 8192 + t) << 7);
  if (dorope) {
    double invf = pow(10000.0, -(double)d / 64.0);
    float ang = (float)(t + pos_off[0]) * (float)invf;
    float cs = (float)cos((double)ang), sn = (float)sin((double)ang);
    op[d]      = c1 * cs - c2 * sn;
    op[d + 64] = c2 * cs + c1 * sn;
  } else {
    op[d]      = c1;
    op[d + 64] = c2;
  }
}

// ---------------------------------------------------------------------------
extern "C" void kernel_launch(void* const* d_in, const int* in_sizes, int n_in,
                              void* d_out, int out_size, void* d_ws, size_t ws_size,
                              hipStream_t stream) {
  const float* x  = (const float*)d_in[0];
  const float* wq = (const float*)d_in[1];
  const float* wk = (const float*)d_in[2];
  const float* wv = (const float*)d_in[3];
  const int* pos  = (const int*)d_in[4];
  float* out = (float*)d_out;

  // workspace layout (163.6 MB total)
  const size_t WS_NEEDED = 134217728ull + 25165824ull + 4194304ull;
  if (ws_size < WS_NEEDED) {
    fallback_kernel<<<dim3(16384, 6), 256, 0, stream>>>(x, wq, wk, wv, pos, out);
    return;
  }

  unsigned short* Ahi = (unsigned short*)d_ws;      // 33554432 bf16 = 67.1 MB
  unsigned short* Alo = Ahi + 33554432;             // 67.1 MB
  unsigned short* Bhi = Alo + 33554432;             // 3072*2048 = 12.6 MB
  unsigned short* Blo = Bhi + 6291456;              // 12.6 MB
  float2* rt = (float2*)(Blo + 6291456);            // 8192*64*8B = 4.2 MB

  prep_kernel<<<2688, 256, 0, stream>>>(x, wq, wk, wv, pos,
                                        Ahi, Alo, Bhi, Blo, rt);
  gemm8_kernel<<<768, 512, 0, stream>>>(Ahi, Alo, Bhi, Blo, rt, out);
}